// Round 4
// baseline (634.755 us; speedup 1.0000x reference)
//
#include <hip/hip_runtime.h>
#include <hip/hip_cooperative_groups.h>

namespace cg = cooperative_groups;

#define NATOMS 768
#define NM1    767
#define DIM    64
#define NC     50
#define GAPF   (5.0f/49.0f)
#define NIGAP  (-49.0f/5.0f)
#define G      1024
#define STEPF  (5.0f/1023.0f)
#define INVSTEP (1023.0f/5.0f)
#define LN2F   0.693147180559945f
#define NBLK   512

// ws layout (float offsets)
#define WS_H     0              // 768*64
#define WS_NW    49152          // 768*64
#define WS_AGGP  98304          // 8*768*64
#define WS_HA    491520         // 768
#define WS_DISTT 492288         // 768*768
#define WS_TT    1082112        // 4 tables * 1024*64 float2

__device__ __forceinline__ float softplus05(float x) {
    float bx = 0.5f * x;
    return (bx > 14.0f) ? x : 2.0f * __logf(1.0f + __expf(bx));
}

// =====================================================================
// ===================== fused cooperative kernel ======================
// =====================================================================
struct P3 { float nw[96 * DIM]; float2 kf[4][96]; };                  // 27648 B
struct P4 { float4 pre[4][64]; float h[4][16 * 65]; float w2[128]; }; // 21248 B
union Smem { float t[4 * 64]; float upd[4][192]; P3 p3; P4 p4; };

__global__ __launch_bounds__(256, 2)
void k_fused(const int* __restrict__ types, const float* __restrict__ dist,
             const int* __restrict__ srcI, const int* __restrict__ dstI,
             const float* __restrict__ emb, const float* __restrict__ w1all,
             const float* __restrict__ pw1, const float* __restrict__ pb1,
             const float* __restrict__ pw2, const float* __restrict__ pb2,
             const float* __restrict__ qw1, const float* __restrict__ qb1,
             const float* __restrict__ qw2, const float* __restrict__ qb2,
             const float* __restrict__ auw1, const float* __restrict__ aub1,
             const float* __restrict__ auw2, const float* __restrict__ aub2,
             const float* __restrict__ row1, const float* __restrict__ rob1,
             const float* __restrict__ row2, const float* __restrict__ rob2,
             float* __restrict__ ws, float* __restrict__ out) {
    cg::grid_group gg = cg::this_grid();
    __shared__ Smem sm;
    const int tid = threadIdx.x, widx = tid >> 6, c = tid & 63;
    const int b = blockIdx.x;
    const int w = b * 4 + widx;                  // global wave id, [0,2048)
    float* h     = ws + WS_H;
    float* nw    = ws + WS_NW;
    float* aggp  = ws + WS_AGGP;
    float* ha    = ws + WS_HA;
    float* distT = ws + WS_DISTT;
    float* TTf   = ws + WS_TT;

    // ---------- phase 1: build 4 lerp tables (2 rows per wave) ----------
    #pragma unroll
    for (int it = 0; it < 2; ++it) {
        const int r = w + it * 2048;             // < 4096
        const int tbl = r >> 10, g = r & 1023;
        const float d = g * STEPF;
        float val;
        if (tbl < 3) {
            const float* W1 = pw1 + tbl * NC * DIM;
            float t1 = pb1[tbl * DIM + c];
            for (int k = 0; k < NC; ++k) {
                float x = d - GAPF * (float)k;
                t1 = fmaf(__expf(NIGAP * x * x), W1[k * DIM + c], t1);
            }
            sm.t[widx * 64 + c] = softplus05(t1);    // wave-local lockstep
            const float* W2 = pw2 + tbl * DIM * DIM;
            val = pb2[tbl * DIM + c];
            #pragma unroll 8
            for (int k = 0; k < DIM; ++k)
                val = fmaf(sm.t[widx * 64 + k], W2[k * DIM + c], val);
        } else {
            val = rob1[c];
            for (int k = 0; k < NC; ++k) {
                float x = d - GAPF * (float)k;
                val = fmaf(__expf(NIGAP * x * x), row1[(2 + k) * DIM + c], val);
            }
        }
        float* TTt = TTf + tbl * (G * DIM * 2);
        TTt[(g * DIM + c) * 2] = val;                       // .x of row g
        if (g > 0) TTt[((g - 1) * DIM + c) * 2 + 1] = val;  // .y of row g-1
    }

    // ---------- phase 2: distT transpose + embed + nw(layer0) ----------
    {
        int row = b;
        for (int cc = tid; cc < NATOMS; cc += 256)
            distT[row * NATOMS + cc] = (cc == row) ? 0.0f
                : dist[cc * NM1 + (row - (row > cc))];
        if (b < 256) {
            row = NBLK + b;
            for (int cc = tid; cc < NATOMS; cc += 256)
                distT[row * NATOMS + cc] = (cc == row) ? 0.0f
                    : dist[cc * NM1 + (row - (row > cc))];
        }
    }
    if (w < NATOMS) {
        float hv = emb[types[w] * DIM + c];
        h[w * DIM + c] = hv;
        sm.t[widx * 64 + c] = hv;                // own wave's region
        float acc = 0.0f;
        #pragma unroll 8
        for (int k = 0; k < DIM; ++k)
            acc = fmaf(sm.t[widx * 64 + k], w1all[k * DIM + c], acc);
        nw[w * DIM + c] = acc;
    }
    gg.sync();

    // ---------- phase 3: conv layers ----------
    const int q = b & 7, jg = b >> 3;            // jg in [0,64)
    const int ibase = q * 96;
    for (int l = 0; l < 3; ++l) {
        { // 3a: edge agg, 3 dest-tiles sharing the staged s_nw chunk
            const float2* TTl = (const float2*)TTf + l * (G * DIM);
            const float4* s4 = (const float4*)(nw + ibase * DIM);
            float4* d4 = (float4*)sm.p3.nw;
            #pragma unroll
            for (int r = 0; r < 6; ++r) d4[tid + r * 256] = s4[tid + r * 256];
            __syncthreads();
            const char* TTb = (const char*)TTl + c * 8;
            #pragma unroll
            for (int tile = 0; tile < 3; ++tile) {
                const int j = (jg + tile * 64) * 4 + widx;
                {
                    float d = distT[j * NATOMS + ibase + c];
                    float pos = d * INVSTEP;
                    int kk = (int)pos;
                    sm.p3.kf[widx][c] = make_float2(__int_as_float(kk * 512), pos - (float)kk);
                    if (c < 32) {
                        float d2 = distT[j * NATOMS + ibase + 64 + c];
                        float pos2 = d2 * INVSTEP;
                        int k2 = (int)pos2;
                        sm.p3.kf[widx][64 + c] = make_float2(__int_as_float(k2 * 512), pos2 - (float)k2);
                    }
                }
                float csum = 0.0f;
                #pragma unroll 4
                for (int it = 0; it < 96; ++it) {
                    float2 kf = sm.p3.kf[widx][it];
                    float2 tt = *(const float2*)(TTb + __float_as_int(kf.x));
                    float e = fmaf(kf.y, tt.y - tt.x, tt.x);
                    csum = fmaf(e, sm.p3.nw[it * DIM + c], csum);
                }
                const int jq = j - ibase;        // remove fake i==j term
                if (jq >= 0 && jq < 96) {
                    float2 kf = sm.p3.kf[widx][jq];
                    float2 tt = *(const float2*)(TTb + __float_as_int(kf.x));
                    float e = fmaf(kf.y, tt.y - tt.x, tt.x);
                    csum -= e * sm.p3.nw[jq * DIM + c];
                }
                aggp[(q * NATOMS + j) * DIM + c] = csum;
            }
        }
        gg.sync();
        // 3c: node update, wave w -> atom w
        if (w < NATOMS) {
            float* sa = sm.upd[widx];            // 192 floats, wave-local
            float a = 0.0f;
            #pragma unroll
            for (int qq = 0; qq < 8; ++qq) a += aggp[(qq * NATOMS + w) * DIM + c];
            sa[c] = a;
            const float* W1q = qw1 + l * DIM * DIM;
            float t = qb1[l * DIM + c];
            #pragma unroll 8
            for (int k = 0; k < DIM; ++k) t = fmaf(sa[k], W1q[k * DIM + c], t);
            sa[64 + c] = softplus05(t);
            const float* W2q = qw2 + l * DIM * DIM;
            float o = qb2[l * DIM + c];
            #pragma unroll 8
            for (int k = 0; k < DIM; ++k) o = fmaf(sa[64 + k], W2q[k * DIM + c], o);
            float hn = h[w * DIM + c] + o;
            h[w * DIM + c] = hn;
            sa[128 + c] = hn;
            if (l < 2) {
                const float* Wn = w1all + (l + 1) * DIM * DIM;
                float v = 0.0f;
                #pragma unroll 8
                for (int k = 0; k < DIM; ++k) v = fmaf(sa[128 + k], Wn[k * DIM + c], v);
                nw[w * DIM + c] = v;
            } else {
                float t2 = aub1[c];
                #pragma unroll 8
                for (int k = 0; k < DIM; ++k) t2 = fmaf(sa[128 + k], auw1[k * DIM + c], t2);
                t2 = ((t2 > 20.0f) ? t2 : __logf(1.0f + __expf(t2))) - LN2F;
                float v = t2 * auw2[c];
                #pragma unroll
                for (int s = 32; s > 0; s >>= 1) v += __shfl_down(v, s, 64);
                if (c == 0) ha[w] = v + aub2[0];
            }
        }
        gg.sync();
    }

    // ---------- phase 4: readout, 16-edge sub-chunks, wave-local ----------
    if (tid < 128) sm.p4.w2[tid] = row2[tid];
    __syncthreads();
    const float2* TTro = (const float2*)TTf + 3 * (G * DIM);
    const char* TTb2 = (const char*)TTro + c * 8;
    const float wa = row1[c], wb = row1[DIM + c];
    const int e2 = (c >> 1) & 15, p2 = c & 1, kh = c >> 5;
    const float bias2 = (kh == 0) ? rob2[p2] : 0.0f;
    for (int rnd = 0; rnd < 5; ++rnd) {
        const int w4 = rnd * 2048 + w;           // 9204 tasks cover all edges
        if (w4 >= 9204) break;                   // no barriers below -> safe
        const int ebase = w4 * 64;
        {
            int eg = ebase + c;
            float d = dist[eg];
            float pos = d * INVSTEP;
            int kk = (int)pos;
            float fa = ha[srcI[eg]], fb = ha[dstI[eg]];
            sm.p4.pre[widx][c] = make_float4(__int_as_float(kk * 512), pos - (float)kk, fa, fb);
        }
        float* sh = sm.p4.h[widx];
        #pragma unroll
        for (int ch = 0; ch < 4; ++ch) {
            #pragma unroll 4
            for (int e = 0; e < 16; ++e) {       // lane = channel
                float4 p = sm.p4.pre[widx][ch * 16 + e];
                float2 tt = *(const float2*)(TTb2 + __float_as_int(p.x));
                float hv = fmaf(p.y, tt.y - tt.x, tt.x);
                hv = fmaf(p.z, wa, hv);
                hv = fmaf(p.w, wb, hv);
                sh[e * 65 + c] = fmaxf(hv, 0.0f);
            }
            // lane = (khalf, edge, logit); half-k dot then combine
            float lsum = bias2;
            #pragma unroll 8
            for (int k8 = 0; k8 < 32; ++k8) {
                int k = kh * 32 + k8;
                lsum = fmaf(sh[e2 * 65 + k], sm.p4.w2[2 * k + p2], lsum);
            }
            lsum += __shfl_xor(lsum, 32, 64);
            float other = __shfl_xor(lsum, 1, 64);
            float m = fmaxf(lsum, other);
            float ea = __expf(lsum - m), eb = __expf(other - m);
            float r = ea / (ea + eb);
            if (c < 32) out[ebase * 2 + ch * 32 + c] = r;    // coalesced 128B
        }
    }
}

// =====================================================================
// ============ fallback path: round-2 proven multi-kernel =============
// =====================================================================
__global__ __launch_bounds__(256)
void k_pre(const int* __restrict__ types, const float* __restrict__ dist,
           const float* __restrict__ emb, const float* __restrict__ w1all,
           const float* __restrict__ pw1, const float* __restrict__ pb1,
           const float* __restrict__ pw2, const float* __restrict__ pb2,
           const float* __restrict__ row1, const float* __restrict__ rob1,
           float* __restrict__ ws) {
    __shared__ float s_t[4 * 64];
    const int tid = threadIdx.x, widx = tid >> 6, c = tid & 63;
    float* h     = ws + WS_H;
    float* nw    = ws + WS_NW;
    float* distT = ws + WS_DISTT;
    float* TTf   = ws + WS_TT;
    const int b = blockIdx.x;
    if (b < 1024) {
        const int w = b * 4 + widx, tbl = w >> 10, g = w & 1023;
        const float d = g * STEPF;
        float val;
        if (tbl < 3) {
            const float* W1 = pw1 + tbl * NC * DIM;
            float t1 = pb1[tbl * DIM + c];
            for (int k = 0; k < NC; ++k) {
                float x = d - GAPF * (float)k;
                t1 = fmaf(__expf(NIGAP * x * x), W1[k * DIM + c], t1);
            }
            s_t[widx * 64 + c] = softplus05(t1);
            __syncthreads();
            const float* W2 = pw2 + tbl * DIM * DIM;
            val = pb2[tbl * DIM + c];
            #pragma unroll 8
            for (int k = 0; k < DIM; ++k)
                val = fmaf(s_t[widx * 64 + k], W2[k * DIM + c], val);
        } else {
            __syncthreads();
            val = rob1[c];
            for (int k = 0; k < NC; ++k) {
                float x = d - GAPF * (float)k;
                val = fmaf(__expf(NIGAP * x * x), row1[(2 + k) * DIM + c], val);
            }
        }
        float* TTt = TTf + tbl * (G * DIM * 2);
        TTt[(g * DIM + c) * 2] = val;
        if (g > 0) TTt[((g - 1) * DIM + c) * 2 + 1] = val;
    } else if (b < 1216) {
        const int i = (b - 1024) * 4 + widx;
        float hv = emb[types[i] * DIM + c];
        h[i * DIM + c] = hv;
        s_t[widx * 64 + c] = hv;
        __syncthreads();
        float acc = 0.0f;
        #pragma unroll 8
        for (int k = 0; k < DIM; ++k)
            acc = fmaf(s_t[widx * 64 + k], w1all[k * DIM + c], acc);
        nw[i * DIM + c] = acc;
    } else {
        const int idx = (b - 1216) * 256 + tid;
        const int j = idx / NATOMS, i = idx - j * NATOMS;
        distT[idx] = (i == j) ? 0.0f : dist[i * NM1 + (j - (j > i))];
    }
}

__global__ __launch_bounds__(256)
void k_edge(const float2* __restrict__ TTl, const float* __restrict__ distT,
            const float* __restrict__ nw, float* __restrict__ aggp) {
    __shared__ __align__(16) float s_nw[96 * DIM];
    __shared__ float2 s_kf[4][96];
    const int tid = threadIdx.x, widx = tid >> 6, c = tid & 63;
    const int jg = blockIdx.x >> 3, q = blockIdx.x & 7;
    const int j = jg * 4 + widx, ibase = q * 96;
    {
        const float4* s4 = (const float4*)(nw + ibase * DIM);
        float4* d4 = (float4*)s_nw;
        #pragma unroll
        for (int r = 0; r < 6; ++r) d4[tid + r * 256] = s4[tid + r * 256];
    }
    {
        float d = distT[j * NATOMS + ibase + c];
        float pos = d * INVSTEP;
        int kk = (int)pos;
        s_kf[widx][c] = make_float2(__int_as_float(kk * 512), pos - (float)kk);
        if (c < 32) {
            float d2 = distT[j * NATOMS + ibase + 64 + c];
            float pos2 = d2 * INVSTEP;
            int k2 = (int)pos2;
            s_kf[widx][64 + c] = make_float2(__int_as_float(k2 * 512), pos2 - (float)k2);
        }
    }
    __syncthreads();
    const char* TTb = (const char*)TTl + c * 8;
    float csum = 0.0f;
    #pragma unroll 4
    for (int it = 0; it < 96; ++it) {
        float2 kf = s_kf[widx][it];
        float2 tt = *(const float2*)(TTb + __float_as_int(kf.x));
        float e = fmaf(kf.y, tt.y - tt.x, tt.x);
        csum = fmaf(e, s_nw[it * DIM + c], csum);
    }
    const int jq = j - ibase;
    if (jq >= 0 && jq < 96) {
        float2 kf = s_kf[widx][jq];
        float2 tt = *(const float2*)(TTb + __float_as_int(kf.x));
        float e = fmaf(kf.y, tt.y - tt.x, tt.x);
        csum -= e * s_nw[jq * DIM + c];
    }
    aggp[(q * NATOMS + j) * DIM + c] = csum;
}

__global__ __launch_bounds__(64)
void k_upd(const float* __restrict__ aggp,
           const float* __restrict__ qw1, const float* __restrict__ qb1,
           const float* __restrict__ qw2, const float* __restrict__ qb2,
           float* __restrict__ h,
           const float* __restrict__ wnext, float* __restrict__ nw,
           const float* __restrict__ auw1, const float* __restrict__ aub1,
           const float* __restrict__ auw2, const float* __restrict__ aub2,
           float* __restrict__ ha, int last) {
    __shared__ float sa[64], ss[64], sh[64];
    const int i = blockIdx.x, c = threadIdx.x;
    float a = 0.0f;
    #pragma unroll
    for (int qq = 0; qq < 8; ++qq) a += aggp[(qq * NATOMS + i) * DIM + c];
    sa[c] = a;
    __syncthreads();
    float t = qb1[c];
    #pragma unroll 8
    for (int k = 0; k < DIM; ++k) t = fmaf(sa[k], qw1[k * DIM + c], t);
    ss[c] = softplus05(t);
    __syncthreads();
    float o = qb2[c];
    #pragma unroll 8
    for (int k = 0; k < DIM; ++k) o = fmaf(ss[k], qw2[k * DIM + c], o);
    float hn = h[i * DIM + c] + o;
    h[i * DIM + c] = hn;
    sh[c] = hn;
    __syncthreads();
    if (!last) {
        float v = 0.0f;
        #pragma unroll 8
        for (int k = 0; k < DIM; ++k) v = fmaf(sh[k], wnext[k * DIM + c], v);
        nw[i * DIM + c] = v;
    } else {
        float t2 = aub1[c];
        #pragma unroll 8
        for (int k = 0; k < DIM; ++k) t2 = fmaf(sh[k], auw1[k * DIM + c], t2);
        t2 = ((t2 > 20.0f) ? t2 : __logf(1.0f + __expf(t2))) - LN2F;
        float v = t2 * auw2[c];
        #pragma unroll
        for (int s = 32; s > 0; s >>= 1) v += __shfl_down(v, s, 64);
        if (c == 0) ha[i] = v + aub2[0];
    }
}

__global__ __launch_bounds__(256)
void k_ro(const float* __restrict__ dist, const int* __restrict__ src,
          const int* __restrict__ dst, const float* __restrict__ ha,
          const float2* __restrict__ TTro,
          const float* __restrict__ row1, const float* __restrict__ row2,
          const float* __restrict__ rob2, float* __restrict__ out) {
    __shared__ float4 s_pre[4][64];
    __shared__ float s_h[4][32 * 65];
    __shared__ float s_w2[128];
    const int tid = threadIdx.x, widx = tid >> 6, c = tid & 63;
    const int base = (blockIdx.x * 4 + widx) * 64;
    if (tid < 128) s_w2[tid] = row2[tid];
    {
        int eg = base + c;
        float d = dist[eg];
        float pos = d * INVSTEP;
        int kk = (int)pos;
        float fa = ha[src[eg]], fb = ha[dst[eg]];
        s_pre[widx][c] = make_float4(__int_as_float(kk * 512), pos - (float)kk, fa, fb);
    }
    __syncthreads();
    const char* TTb = (const char*)TTro + c * 8;
    const float wa = row1[c], wb = row1[DIM + c];
    const int e2 = c >> 1, p2 = c & 1;
    const float bias2 = rob2[p2];
    #pragma unroll
    for (int ch = 0; ch < 2; ++ch) {
        #pragma unroll 2
        for (int e = 0; e < 32; ++e) {
            float4 p = s_pre[widx][ch * 32 + e];
            float2 tt = *(const float2*)(TTb + __float_as_int(p.x));
            float hv = fmaf(p.y, tt.y - tt.x, tt.x);
            hv = fmaf(p.z, wa, hv);
            hv = fmaf(p.w, wb, hv);
            s_h[widx][e * 65 + c] = fmaxf(hv, 0.0f);
        }
        float lsum = bias2;
        #pragma unroll 8
        for (int k = 0; k < DIM; ++k)
            lsum = fmaf(s_h[widx][e2 * 65 + k], s_w2[2 * k + p2], lsum);
        float other = __shfl_xor(lsum, 1, 64);
        float m = fmaxf(lsum, other);
        float ea = __expf(lsum - m), eb = __expf(other - m);
        out[base * 2 + ch * 64 + c] = ea / (ea + eb);
    }
}

extern "C" void kernel_launch(void* const* d_in, const int* in_sizes, int n_in,
                              void* d_out, int out_size, void* d_ws, size_t ws_size,
                              hipStream_t stream) {
    const int*   types = (const int*)d_in[0];
    const float* dist  = (const float*)d_in[1];
    const int*   srcI  = (const int*)d_in[2];
    const int*   dstI  = (const int*)d_in[3];
    const float* emb   = (const float*)d_in[4];
    const float* w1    = (const float*)d_in[5];
    const float* pw1   = (const float*)d_in[6];
    const float* pb1   = (const float*)d_in[7];
    const float* pw2   = (const float*)d_in[8];
    const float* pb2   = (const float*)d_in[9];
    const float* qw1   = (const float*)d_in[10];
    const float* qb1   = (const float*)d_in[11];
    const float* qw2   = (const float*)d_in[12];
    const float* qb2   = (const float*)d_in[13];
    const float* auw1  = (const float*)d_in[14];
    const float* aub1  = (const float*)d_in[15];
    const float* auw2  = (const float*)d_in[16];
    const float* aub2  = (const float*)d_in[17];
    const float* row1  = (const float*)d_in[18];
    const float* rob1  = (const float*)d_in[19];
    const float* row2  = (const float*)d_in[20];
    const float* rob2  = (const float*)d_in[21];

    float* ws   = (float*)d_ws;
    float* outp = (float*)d_out;

    // ---- pre-flight: is a 512-block cooperative launch valid here? ----
    int coopOK = 0;
    {
        int dev = 0;
        if (hipGetDevice(&dev) == hipSuccess) {
            hipDeviceProp_t prop;
            if (hipGetDeviceProperties(&prop, dev) == hipSuccess &&
                prop.cooperativeLaunch) {
                int maxB = 0;
                if (hipOccupancyMaxActiveBlocksPerMultiprocessor(
                        &maxB, (const void*)k_fused, 256, 0) == hipSuccess &&
                    (long)maxB * prop.multiProcessorCount >= NBLK)
                    coopOK = 1;
            }
        }
    }
    if (coopOK) {
        void* args[] = { (void*)&types, (void*)&dist, (void*)&srcI, (void*)&dstI,
                         (void*)&emb, (void*)&w1, (void*)&pw1, (void*)&pb1,
                         (void*)&pw2, (void*)&pb2, (void*)&qw1, (void*)&qb1,
                         (void*)&qw2, (void*)&qb2, (void*)&auw1, (void*)&aub1,
                         (void*)&auw2, (void*)&aub2, (void*)&row1, (void*)&rob1,
                         (void*)&row2, (void*)&rob2, (void*)&ws, (void*)&outp };
        if (hipLaunchCooperativeKernel((void*)k_fused, dim3(NBLK), dim3(256),
                                       args, 0, stream) == hipSuccess)
            return;
    }

    // ---- fallback: proven round-2 multi-kernel pipeline ----
    const float2* TT = (const float2*)(ws + WS_TT);
    k_pre<<<3520, 256, 0, stream>>>(types, dist, emb, w1, pw1, pb1, pw2, pb2,
                                    row1, rob1, ws);
    for (int l = 0; l < 3; ++l) {
        k_edge<<<1536, 256, 0, stream>>>(TT + l * G * DIM, ws + WS_DISTT,
                                         ws + WS_NW, ws + WS_AGGP);
        k_upd<<<768, 64, 0, stream>>>(ws + WS_AGGP,
            qw1 + l * DIM * DIM, qb1 + l * DIM,
            qw2 + l * DIM * DIM, qb2 + l * DIM,
            ws + WS_H,
            (l < 2) ? (w1 + (l + 1) * DIM * DIM) : w1, ws + WS_NW,
            auw1, aub1, auw2, aub2, ws + WS_HA, (l == 2) ? 1 : 0);
    }
    k_ro<<<2301, 256, 0, stream>>>(dist, srcI, dstI, ws + WS_HA, TT + 3 * G * DIM,
                                   row1, row2, rob2, outp);
}

// Round 5
// 219.123 us; speedup vs baseline: 2.8968x; 2.8968x over previous
//
#include <hip/hip_runtime.h>

#define NATOMS 768
#define NM1    767
#define NEDGE  (768*767)       // 589056
#define DIM    64
#define NC     50
#define GAPF   (5.0f/49.0f)
#define NIGAP  (-49.0f/5.0f)
#define G      512
#define STEPF  (5.0f/511.0f)
#define INVSTEP (511.0f/5.0f)
#define LN2F   0.693147180559945f

// ws layout (float offsets)
#define WS_H     0              // 768*64
#define WS_NWA   49152          // 768*64  (nw ping)
#define WS_NWB   98304          // 768*64  (nw pong)
#define WS_HA    147456         // 768
#define WS_DISTT 148224         // 768*768
#define WS_TT    738048         // 4 tables * 512*64 float2 = 262144 floats

__device__ __forceinline__ float softplus05(float x) {
    float bx = 0.5f * x;
    return (bx > 14.0f) ? x : 2.0f * __logf(1.0f + __expf(bx));
}
__device__ __forceinline__ int lane_bcast_i(int v, int l) {
    return __builtin_amdgcn_readlane(v, l);
}
__device__ __forceinline__ float lane_bcast_f(float v, int l) {
    return __uint_as_float((unsigned)__builtin_amdgcn_readlane((int)__float_as_uint(v), l));
}

// ============ prologue: tables(G=512) + embed/nw0 + dist transpose ============
// blocks [0,512): 4 tables x 512 rows, wave per (tbl,g)
// blocks [512,704): embed + nodew layer0, wave per atom
// blocks [704,3008): distT[j][i] transpose (diag = 0)
__global__ __launch_bounds__(256)
void k_pre(const int* __restrict__ types, const float* __restrict__ dist,
           const float* __restrict__ emb, const float* __restrict__ w1all,
           const float* __restrict__ pw1, const float* __restrict__ pb1,
           const float* __restrict__ pw2, const float* __restrict__ pb2,
           const float* __restrict__ row1, const float* __restrict__ rob1,
           float* __restrict__ ws) {
    __shared__ float s_t[4 * 64];
    const int tid = threadIdx.x, widx = tid >> 6, c = tid & 63;
    float* h     = ws + WS_H;
    float* nw    = ws + WS_NWA;
    float* distT = ws + WS_DISTT;
    float* TTf   = ws + WS_TT;
    const int b = blockIdx.x;

    if (b < 512) {
        const int w = b * 4 + widx, tbl = w >> 9, g = w & 511;
        const float d = g * STEPF;
        float val;
        if (tbl < 3) {
            const float* W1 = pw1 + tbl * NC * DIM;
            float t1 = pb1[tbl * DIM + c];
            for (int k = 0; k < NC; ++k) {
                float x = d - GAPF * (float)k;
                t1 = fmaf(__expf(NIGAP * x * x), W1[k * DIM + c], t1);
            }
            s_t[widx * 64 + c] = softplus05(t1);     // wave-local lockstep
            const float* W2 = pw2 + tbl * DIM * DIM;
            val = pb2[tbl * DIM + c];
            #pragma unroll 8
            for (int k = 0; k < DIM; ++k)
                val = fmaf(s_t[widx * 64 + k], W2[k * DIM + c], val);
        } else {
            val = rob1[c];
            for (int k = 0; k < NC; ++k) {
                float x = d - GAPF * (float)k;
                val = fmaf(__expf(NIGAP * x * x), row1[(2 + k) * DIM + c], val);
            }
        }
        // paired layout: row g holds (T[g][c], T[g+1][c]) as float2
        float* TTt = TTf + tbl * (G * DIM * 2);
        TTt[(g * DIM + c) * 2] = val;
        if (g > 0) TTt[((g - 1) * DIM + c) * 2 + 1] = val;
    } else if (b < 704) {
        const int i = (b - 512) * 4 + widx;
        float hv = emb[types[i] * DIM + c];
        h[i * DIM + c] = hv;
        s_t[widx * 64 + c] = hv;                     // wave-local
        float acc = 0.0f;
        #pragma unroll 8
        for (int k = 0; k < DIM; ++k)
            acc = fmaf(s_t[widx * 64 + k], w1all[k * DIM + c], acc);
        nw[i * DIM + c] = acc;
    } else {
        const int idx = (b - 704) * 256 + tid;       // < 768*768
        const int j = idx / NATOMS, i = idx - j * NATOMS;
        distT[idx] = (i == j) ? 0.0f : dist[i * NM1 + (j - (j > i))];
    }
}

// ============ edge aggregation + node update, block owns dest j ============
// 768 blocks x 4 waves; wave widx covers sources [widx*192, widx*192+192).
// Partials combined in LDS; wave 0 runs the node MLP and writes h / nw / ha.
__global__ __launch_bounds__(256, 3)
void k_edgeupd(const float2* __restrict__ TTl, const float* __restrict__ distT,
               const float* __restrict__ nwin,
               const float* __restrict__ qw1, const float* __restrict__ qb1,
               const float* __restrict__ qw2, const float* __restrict__ qb2,
               float* __restrict__ h,
               const float* __restrict__ wnext, float* __restrict__ nwout,
               const float* __restrict__ auw1, const float* __restrict__ aub1,
               const float* __restrict__ auw2, const float* __restrict__ aub2,
               float* __restrict__ ha, int last) {
    __shared__ float s_part[4][64];
    __shared__ float s_upd[192];
    const int tid = threadIdx.x, widx = tid >> 6, c = tid & 63;
    const int j = blockIdx.x;

    const char* TTb = (const char*)TTl + c * 8;
    float csum = 0.0f;
    #pragma unroll
    for (int ch = 0; ch < 3; ++ch) {
        const int s0 = widx * 192 + ch * 64;
        // per-lane (g,f) for sources s0..s0+63
        float d = distT[j * NATOMS + s0 + c];
        float pos = d * INVSTEP;
        int g = (int)pos;
        g = (g > 510) ? 510 : g;
        float f = pos - (float)g;
        int kx = g * 512;                            // byte offset of row pair
        #pragma unroll 8
        for (int it = 0; it < 64; ++it) {
            int kxu = lane_bcast_i(kx, it);
            float fu = lane_bcast_f(f, it);
            float2 tt = *(const float2*)(TTb + kxu);
            float e = fmaf(fu, tt.y - tt.x, tt.x);
            csum = fmaf(e, nwin[(s0 + it) * DIM + c], csum);
        }
    }
    s_part[widx][c] = csum;
    __syncthreads();

    if (widx == 0) {
        float tot = s_part[0][c] + s_part[1][c] + s_part[2][c] + s_part[3][c];
        // remove fake i==j term: distT diag=0 -> g=0,f=0 -> e = T[0][c] exactly
        float2 t0 = *(const float2*)TTb;
        tot -= t0.x * nwin[j * DIM + c];
        // node MLP (wave-local LDS, lockstep)
        s_upd[c] = tot;
        float t = qb1[c];
        #pragma unroll 8
        for (int k = 0; k < DIM; ++k) t = fmaf(s_upd[k], qw1[k * DIM + c], t);
        s_upd[64 + c] = softplus05(t);
        float o = qb2[c];
        #pragma unroll 8
        for (int k = 0; k < DIM; ++k) o = fmaf(s_upd[64 + k], qw2[k * DIM + c], o);
        float hn = h[j * DIM + c] + o;
        h[j * DIM + c] = hn;
        s_upd[128 + c] = hn;
        if (!last) {
            float v = 0.0f;
            #pragma unroll 8
            for (int k = 0; k < DIM; ++k) v = fmaf(s_upd[128 + k], wnext[k * DIM + c], v);
            nwout[j * DIM + c] = v;
        } else {
            float t2 = aub1[c];
            #pragma unroll 8
            for (int k = 0; k < DIM; ++k) t2 = fmaf(s_upd[128 + k], auw1[k * DIM + c], t2);
            t2 = ((t2 > 20.0f) ? t2 : __logf(1.0f + __expf(t2))) - LN2F;
            float v = t2 * auw2[c];
            #pragma unroll
            for (int s = 32; s > 0; s >>= 1) v += __shfl_down(v, s, 64);
            if (c == 0) ha[j] = v + aub2[0];
        }
    }
}

// ============ readout (round-4-verified logic, standalone) ============
// 2301 blocks x 4 waves = 9204 wave-tasks x 64 edges = 589056 exactly.
__global__ __launch_bounds__(256)
void k_ro(const float* __restrict__ dist, const int* __restrict__ src,
          const int* __restrict__ dst, const float* __restrict__ ha,
          const float2* __restrict__ TTro,
          const float* __restrict__ row1, const float* __restrict__ row2,
          const float* __restrict__ rob2, float* __restrict__ out) {
    __shared__ float4 s_pre[4][64];
    __shared__ float s_h[4][16 * 65];
    __shared__ float s_w2[128];
    const int tid = threadIdx.x, widx = tid >> 6, c = tid & 63;
    if (tid < 128) s_w2[tid] = row2[tid];
    __syncthreads();
    const int ebase = (blockIdx.x * 4 + widx) * 64;
    {
        int eg = ebase + c;
        float d = dist[eg];
        float pos = d * INVSTEP;
        int kk = (int)pos;
        kk = (kk > 510) ? 510 : kk;
        float fa = ha[src[eg]], fb = ha[dst[eg]];
        s_pre[widx][c] = make_float4(__int_as_float(kk * 512), pos - (float)kk, fa, fb);
    }
    const char* TTb2 = (const char*)TTro + c * 8;
    const float wa = row1[c], wb = row1[DIM + c];
    const int e2 = (c >> 1) & 15, p2 = c & 1, kh = c >> 5;
    const float bias2 = (kh == 0) ? rob2[p2] : 0.0f;
    float* sh = s_h[widx];
    #pragma unroll
    for (int ch = 0; ch < 4; ++ch) {
        #pragma unroll 4
        for (int e = 0; e < 16; ++e) {               // lane = channel
            float4 p = s_pre[widx][ch * 16 + e];
            float2 tt = *(const float2*)(TTb2 + __float_as_int(p.x));
            float hv = fmaf(p.y, tt.y - tt.x, tt.x);
            hv = fmaf(p.z, wa, hv);
            hv = fmaf(p.w, wb, hv);
            sh[e * 65 + c] = fmaxf(hv, 0.0f);
        }
        // lane = (khalf, edge, logit); half-k dot then combine
        float lsum = bias2;
        #pragma unroll 8
        for (int k8 = 0; k8 < 32; ++k8) {
            int k = kh * 32 + k8;
            lsum = fmaf(sh[e2 * 65 + k], s_w2[2 * k + p2], lsum);
        }
        lsum += __shfl_xor(lsum, 32, 64);
        float other = __shfl_xor(lsum, 1, 64);
        float m = fmaxf(lsum, other);
        float ea = __expf(lsum - m), eb = __expf(other - m);
        float r = ea / (ea + eb);
        if (c < 32) out[ebase * 2 + ch * 32 + c] = r;
    }
}

extern "C" void kernel_launch(void* const* d_in, const int* in_sizes, int n_in,
                              void* d_out, int out_size, void* d_ws, size_t ws_size,
                              hipStream_t stream) {
    const int*   types = (const int*)d_in[0];
    const float* dist  = (const float*)d_in[1];
    const int*   srcI  = (const int*)d_in[2];
    const int*   dstI  = (const int*)d_in[3];
    const float* emb   = (const float*)d_in[4];
    const float* w1    = (const float*)d_in[5];
    const float* pw1   = (const float*)d_in[6];
    const float* pb1   = (const float*)d_in[7];
    const float* pw2   = (const float*)d_in[8];
    const float* pb2   = (const float*)d_in[9];
    const float* qw1   = (const float*)d_in[10];
    const float* qb1   = (const float*)d_in[11];
    const float* qw2   = (const float*)d_in[12];
    const float* qb2   = (const float*)d_in[13];
    const float* auw1  = (const float*)d_in[14];
    const float* aub1  = (const float*)d_in[15];
    const float* auw2  = (const float*)d_in[16];
    const float* aub2  = (const float*)d_in[17];
    const float* row1  = (const float*)d_in[18];
    const float* rob1  = (const float*)d_in[19];
    const float* row2  = (const float*)d_in[20];
    const float* rob2  = (const float*)d_in[21];

    float* ws   = (float*)d_ws;
    float* outp = (float*)d_out;
    const float2* TT = (const float2*)(ws + WS_TT);
    float* nwbuf[2] = { ws + WS_NWA, ws + WS_NWB };

    k_pre<<<3008, 256, 0, stream>>>(types, dist, emb, w1, pw1, pb1, pw2, pb2,
                                    row1, rob1, ws);
    for (int l = 0; l < 3; ++l) {
        k_edgeupd<<<768, 256, 0, stream>>>(TT + l * (G * DIM),
            ws + WS_DISTT, nwbuf[l & 1],
            qw1 + l * DIM * DIM, qb1 + l * DIM,
            qw2 + l * DIM * DIM, qb2 + l * DIM,
            ws + WS_H,
            (l < 2) ? (w1 + (l + 1) * DIM * DIM) : w1, nwbuf[(l + 1) & 1],
            auw1, aub1, auw2, aub2, ws + WS_HA, (l == 2) ? 1 : 0);
    }
    k_ro<<<2301, 256, 0, stream>>>(dist, srcI, dstI, ws + WS_HA, TT + 3 * (G * DIM),
                                   row1, row2, rob2, outp);
}

// Round 6
// 214.935 us; speedup vs baseline: 2.9532x; 1.0195x over previous
//
#include <hip/hip_runtime.h>

#define NATOMS 768
#define NM1    767
#define NEDGE  (768*767)       // 589056
#define DIM    64
#define NC     50
#define GAPF   (5.0f/49.0f)
#define NIGAP  (-49.0f/5.0f)
#define G      512
#define STEPF  (5.0f/511.0f)
#define INVSTEP (511.0f/5.0f)
#define LN2F   0.693147180559945f

// ws layout (float offsets)
#define WS_H     0              // 768*64
#define WS_NWA   49152          // 768*64  (nw ping)
#define WS_NWB   98304          // 768*64  (nw pong)
#define WS_HA    147456         // 768
#define WS_DISTT 148224         // 768*768
#define WS_TT    738048         // 4 tables * 512*64 float2 = 262144 floats

__device__ __forceinline__ float softplus05(float x) {
    float bx = 0.5f * x;
    return (bx > 14.0f) ? x : 2.0f * __logf(1.0f + __expf(bx));
}
__device__ __forceinline__ int lane_bcast_i(int v, int l) {
    return __builtin_amdgcn_readlane(v, l);
}
__device__ __forceinline__ float lane_bcast_f(float v, int l) {
    return __uint_as_float((unsigned)__builtin_amdgcn_readlane((int)__float_as_uint(v), l));
}

// ============ prologue: tables(G=512) + embed/nw0 + dist transpose ============
__global__ __launch_bounds__(256)
void k_pre(const int* __restrict__ types, const float* __restrict__ dist,
           const float* __restrict__ emb, const float* __restrict__ w1all,
           const float* __restrict__ pw1, const float* __restrict__ pb1,
           const float* __restrict__ pw2, const float* __restrict__ pb2,
           const float* __restrict__ row1, const float* __restrict__ rob1,
           float* __restrict__ ws) {
    __shared__ float s_t[4 * 64];
    const int tid = threadIdx.x, widx = tid >> 6, c = tid & 63;
    float* h     = ws + WS_H;
    float* nw    = ws + WS_NWA;
    float* distT = ws + WS_DISTT;
    float* TTf   = ws + WS_TT;
    const int b = blockIdx.x;

    if (b < 512) {
        const int w = b * 4 + widx, tbl = w >> 9, g = w & 511;
        const float d = g * STEPF;
        float val;
        if (tbl < 3) {
            const float* W1 = pw1 + tbl * NC * DIM;
            float t1 = pb1[tbl * DIM + c];
            for (int k = 0; k < NC; ++k) {
                float x = d - GAPF * (float)k;
                t1 = fmaf(__expf(NIGAP * x * x), W1[k * DIM + c], t1);
            }
            s_t[widx * 64 + c] = softplus05(t1);     // wave-local lockstep
            const float* W2 = pw2 + tbl * DIM * DIM;
            val = pb2[tbl * DIM + c];
            #pragma unroll 8
            for (int k = 0; k < DIM; ++k)
                val = fmaf(s_t[widx * 64 + k], W2[k * DIM + c], val);
        } else {
            val = rob1[c];
            for (int k = 0; k < NC; ++k) {
                float x = d - GAPF * (float)k;
                val = fmaf(__expf(NIGAP * x * x), row1[(2 + k) * DIM + c], val);
            }
        }
        // paired layout: row g holds (T[g][c], T[g+1][c]) as float2
        float* TTt = TTf + tbl * (G * DIM * 2);
        TTt[(g * DIM + c) * 2] = val;
        if (g > 0) TTt[((g - 1) * DIM + c) * 2 + 1] = val;
    } else if (b < 704) {
        const int i = (b - 512) * 4 + widx;
        float hv = emb[types[i] * DIM + c];
        h[i * DIM + c] = hv;
        s_t[widx * 64 + c] = hv;                     // wave-local
        float acc = 0.0f;
        #pragma unroll 8
        for (int k = 0; k < DIM; ++k)
            acc = fmaf(s_t[widx * 64 + k], w1all[k * DIM + c], acc);
        nw[i * DIM + c] = acc;
    } else {
        const int idx = (b - 704) * 256 + tid;       // < 768*768
        const int j = idx / NATOMS, i = idx - j * NATOMS;
        distT[idx] = (i == j) ? 0.0f : dist[i * NM1 + (j - (j > i))];
    }
}

// ============ edge aggregation + node update, block owns dest j ============
// 768 blocks x 8 waves; wave widx covers sources [widx*96, widx*96+96)
// as a 64-chunk + 32-chunk. Partials combined in LDS; wave 0 runs the
// node MLP and writes h / nw / ha.
__global__ __launch_bounds__(512)
void k_edgeupd(const float2* __restrict__ TTl, const float* __restrict__ distT,
               const float* __restrict__ nwin,
               const float* __restrict__ qw1, const float* __restrict__ qb1,
               const float* __restrict__ qw2, const float* __restrict__ qb2,
               float* __restrict__ h,
               const float* __restrict__ wnext, float* __restrict__ nwout,
               const float* __restrict__ auw1, const float* __restrict__ aub1,
               const float* __restrict__ auw2, const float* __restrict__ aub2,
               float* __restrict__ ha, int last) {
    __shared__ float s_part[8][64];
    __shared__ float s_upd[192];
    const int tid = threadIdx.x, widx = tid >> 6, c = tid & 63;
    const int j = blockIdx.x;
    const int s0 = widx * 96;

    const char* TTb = (const char*)TTl + c * 8;
    float csum = 0.0f;
    { // ---- chunk A: sources s0 .. s0+63, lane c holds (g,f) of s0+c ----
        float d = distT[j * NATOMS + s0 + c];
        float pos = d * INVSTEP;
        int g = (int)pos;
        g = (g < 0) ? 0 : ((g > 510) ? 510 : g);
        float f = pos - (float)g;
        int kx = g * 512;                            // byte offset of row pair
        #pragma unroll 8
        for (int it = 0; it < 64; ++it) {
            int kxu = lane_bcast_i(kx, it);
            float fu = lane_bcast_f(f, it);
            float2 tt = *(const float2*)(TTb + kxu);
            float e = fmaf(fu, tt.y - tt.x, tt.x);
            csum = fmaf(e, nwin[(s0 + it) * DIM + c], csum);
        }
    }
    { // ---- chunk B: sources s0+64 .. s0+95 (32), lanes mirrored via c&31 ----
        float d = distT[j * NATOMS + s0 + 64 + (c & 31)];
        float pos = d * INVSTEP;
        int g = (int)pos;
        g = (g < 0) ? 0 : ((g > 510) ? 510 : g);
        float f = pos - (float)g;
        int kx = g * 512;
        #pragma unroll 8
        for (int it = 0; it < 32; ++it) {
            int kxu = lane_bcast_i(kx, it);
            float fu = lane_bcast_f(f, it);
            float2 tt = *(const float2*)(TTb + kxu);
            float e = fmaf(fu, tt.y - tt.x, tt.x);
            csum = fmaf(e, nwin[(s0 + 64 + it) * DIM + c], csum);
        }
    }
    s_part[widx][c] = csum;
    __syncthreads();

    if (widx == 0) {
        float tot = 0.0f;
        #pragma unroll
        for (int w8 = 0; w8 < 8; ++w8) tot += s_part[w8][c];
        // remove fake i==j term: distT diag=0 -> g=0,f=0 -> e = T[0][c] exactly
        float2 t0 = *(const float2*)TTb;
        tot -= t0.x * nwin[j * DIM + c];
        // node MLP (wave-local LDS, lockstep)
        s_upd[c] = tot;
        float t = qb1[c];
        #pragma unroll 8
        for (int k = 0; k < DIM; ++k) t = fmaf(s_upd[k], qw1[k * DIM + c], t);
        s_upd[64 + c] = softplus05(t);
        float o = qb2[c];
        #pragma unroll 8
        for (int k = 0; k < DIM; ++k) o = fmaf(s_upd[64 + k], qw2[k * DIM + c], o);
        float hn = h[j * DIM + c] + o;
        h[j * DIM + c] = hn;
        s_upd[128 + c] = hn;
        if (!last) {
            float v = 0.0f;
            #pragma unroll 8
            for (int k = 0; k < DIM; ++k) v = fmaf(s_upd[128 + k], wnext[k * DIM + c], v);
            nwout[j * DIM + c] = v;
        } else {
            float t2 = aub1[c];
            #pragma unroll 8
            for (int k = 0; k < DIM; ++k) t2 = fmaf(s_upd[128 + k], auw1[k * DIM + c], t2);
            t2 = ((t2 > 20.0f) ? t2 : __logf(1.0f + __expf(t2))) - LN2F;
            float v = t2 * auw2[c];
            #pragma unroll
            for (int s = 32; s > 0; s >>= 1) v += __shfl_down(v, s, 64);
            if (c == 0) ha[j] = v + aub2[0];
        }
    }
}

// ============ readout (verified round-5 logic) ============
__global__ __launch_bounds__(256)
void k_ro(const float* __restrict__ dist, const int* __restrict__ src,
          const int* __restrict__ dst, const float* __restrict__ ha,
          const float2* __restrict__ TTro,
          const float* __restrict__ row1, const float* __restrict__ row2,
          const float* __restrict__ rob2, float* __restrict__ out) {
    __shared__ float4 s_pre[4][64];
    __shared__ float s_h[4][16 * 65];
    __shared__ float s_w2[128];
    const int tid = threadIdx.x, widx = tid >> 6, c = tid & 63;
    if (tid < 128) s_w2[tid] = row2[tid];
    __syncthreads();
    const int ebase = (blockIdx.x * 4 + widx) * 64;
    {
        int eg = ebase + c;
        float d = dist[eg];
        float pos = d * INVSTEP;
        int kk = (int)pos;
        kk = (kk < 0) ? 0 : ((kk > 510) ? 510 : kk);
        float fa = ha[src[eg]], fb = ha[dst[eg]];
        s_pre[widx][c] = make_float4(__int_as_float(kk * 512), pos - (float)kk, fa, fb);
    }
    const char* TTb2 = (const char*)TTro + c * 8;
    const float wa = row1[c], wb = row1[DIM + c];
    const int e2 = (c >> 1) & 15, p2 = c & 1, kh = c >> 5;
    const float bias2 = (kh == 0) ? rob2[p2] : 0.0f;
    float* sh = s_h[widx];
    #pragma unroll
    for (int ch = 0; ch < 4; ++ch) {
        #pragma unroll 4
        for (int e = 0; e < 16; ++e) {               // lane = channel
            float4 p = s_pre[widx][ch * 16 + e];
            float2 tt = *(const float2*)(TTb2 + __float_as_int(p.x));
            float hv = fmaf(p.y, tt.y - tt.x, tt.x);
            hv = fmaf(p.z, wa, hv);
            hv = fmaf(p.w, wb, hv);
            sh[e * 65 + c] = fmaxf(hv, 0.0f);
        }
        // lane = (khalf, edge, logit); half-k dot then combine
        float lsum = bias2;
        #pragma unroll 8
        for (int k8 = 0; k8 < 32; ++k8) {
            int k = kh * 32 + k8;
            lsum = fmaf(sh[e2 * 65 + k], s_w2[2 * k + p2], lsum);
        }
        lsum += __shfl_xor(lsum, 32, 64);
        float other = __shfl_xor(lsum, 1, 64);
        float m = fmaxf(lsum, other);
        float ea = __expf(lsum - m), eb = __expf(other - m);
        float r = ea / (ea + eb);
        if (c < 32) out[ebase * 2 + ch * 32 + c] = r;
    }
}

extern "C" void kernel_launch(void* const* d_in, const int* in_sizes, int n_in,
                              void* d_out, int out_size, void* d_ws, size_t ws_size,
                              hipStream_t stream) {
    const int*   types = (const int*)d_in[0];
    const float* dist  = (const float*)d_in[1];
    const int*   srcI  = (const int*)d_in[2];
    const int*   dstI  = (const int*)d_in[3];
    const float* emb   = (const float*)d_in[4];
    const float* w1    = (const float*)d_in[5];
    const float* pw1   = (const float*)d_in[6];
    const float* pb1   = (const float*)d_in[7];
    const float* pw2   = (const float*)d_in[8];
    const float* pb2   = (const float*)d_in[9];
    const float* qw1   = (const float*)d_in[10];
    const float* qb1   = (const float*)d_in[11];
    const float* qw2   = (const float*)d_in[12];
    const float* qb2   = (const float*)d_in[13];
    const float* auw1  = (const float*)d_in[14];
    const float* aub1  = (const float*)d_in[15];
    const float* auw2  = (const float*)d_in[16];
    const float* aub2  = (const float*)d_in[17];
    const float* row1  = (const float*)d_in[18];
    const float* rob1  = (const float*)d_in[19];
    const float* row2  = (const float*)d_in[20];
    const float* rob2  = (const float*)d_in[21];

    float* ws   = (float*)d_ws;
    float* outp = (float*)d_out;
    const float2* TT = (const float2*)(ws + WS_TT);
    float* nwbuf[2] = { ws + WS_NWA, ws + WS_NWB };

    k_pre<<<3008, 256, 0, stream>>>(types, dist, emb, w1, pw1, pb1, pw2, pb2,
                                    row1, rob1, ws);
    for (int l = 0; l < 3; ++l) {
        k_edgeupd<<<768, 512, 0, stream>>>(TT + l * (G * DIM),
            ws + WS_DISTT, nwbuf[l & 1],
            qw1 + l * DIM * DIM, qb1 + l * DIM,
            qw2 + l * DIM * DIM, qb2 + l * DIM,
            ws + WS_H,
            (l < 2) ? (w1 + (l + 1) * DIM * DIM) : w1, nwbuf[(l + 1) & 1],
            auw1, aub1, auw2, aub2, ws + WS_HA, (l == 2) ? 1 : 0);
    }
    k_ro<<<2301, 256, 0, stream>>>(dist, srcI, dstI, ws + WS_HA, TT + 3 * (G * DIM),
                                   row1, row2, rob2, outp);
}